// Round 3
// baseline (96.792 us; speedup 1.0000x reference)
//
#include <hip/hip_runtime.h>
#include <math.h>

#define NROWS 65536
#define DIM   256
#define NCLS  512
#define CPW   128                 // rows per class
#define BM    64                  // rows per k_main tile
#define NBLK  1024                // NROWS / BM

// ws layout
#define WS_CNT_I   0              // 512 ints
#define WS_IDX_I   512            // 65536 ints
#define WS_QPACK_F 66048          // 131072 ushorts (256 KB)
#define WS_LOSSP_F 131584         // 1024 floats
#define WS_APACK_F 132608         // 33,554,432 ushorts (32 MB)
#define WS_NEEDED  (WS_APACK_F * 4ull + (size_t)NBLK * 32 * 64 * 8 * 2)

typedef float f32x4  __attribute__((ext_vector_type(4)));
typedef short bf16x8 __attribute__((ext_vector_type(8)));
typedef unsigned short u16;

__device__ inline u16 f2bf(float f) {
  unsigned u = __float_as_uint(f);
  u += 0x7FFFu + ((u >> 16) & 1u);      // RNE (inputs finite)
  return (u16)(u >> 16);
}
__device__ inline unsigned pack2(float a, float b) {
  return (unsigned)f2bf(a) | ((unsigned)f2bf(b) << 16);
}

// ---------------- kernel 0: zero class cursors ----------------
__global__ __launch_bounds__(512) void k_zero(int* __restrict__ cnt) {
  cnt[threadIdx.x] = 0;
}

// ---------------- kernel 1: scatter row indices by class ----------------
__global__ __launch_bounds__(256) void k_scatter(
    const int* __restrict__ tgt, int* __restrict__ cnt, int* __restrict__ idx) {
  const int row = blockIdx.x * 256 + threadIdx.x;
  const int c = tgt[row];
  const int p = atomicAdd(&cnt[c], 1);
  if (p < CPW) idx[c * CPW + p] = row;
}

// ---- kernel 2: per-class sums -> qpack B-frags; optionally write normalized
// ---- bf16 A in MFMA tile layout [tile][kg][r][8] (class-grouped row order)
template <bool WRITE_A>
__global__ __launch_bounds__(512) void k_csum(
    const float* __restrict__ x, const int* __restrict__ idx,
    u16* __restrict__ qpack, u16* __restrict__ apack) {
  __shared__ int   sidx[CPW];
  __shared__ float wpart[8][DIM];     // 8 KB
  __shared__ float wsum[4];
  __shared__ float ninv_s;
  const int c    = blockIdx.x;
  const int tid  = threadIdx.x;
  const int w    = tid >> 6;
  const int lane = tid & 63;
  if (tid < CPW) sidx[tid] = idx[c * CPW + tid];
  __syncthreads();

  float4 vs = make_float4(0.f, 0.f, 0.f, 0.f);
  #pragma unroll 4
  for (int i = 0; i < 16; ++i) {
    const int rl  = w * 16 + i;
    const int row = sidx[rl];
    const float4 v = *reinterpret_cast<const float4*>(x + (size_t)row * DIM + lane * 4);
    vs.x += v.x; vs.y += v.y; vs.z += v.z; vs.w += v.w;
    if constexpr (WRITE_A) {
      float ss = v.x * v.x + v.y * v.y + v.z * v.z + v.w * v.w;
      ss += __shfl_xor(ss, 1, 64);
      ss += __shfl_xor(ss, 2, 64);
      ss += __shfl_xor(ss, 4, 64);
      ss += __shfl_xor(ss, 8, 64);
      ss += __shfl_xor(ss, 16, 64);
      ss += __shfl_xor(ss, 32, 64);
      const float rn = rsqrtf(fmaxf(ss, 1e-30f));
      const int slot = c * CPW + rl;        // class-grouped global row order
      const int t  = slot >> 6;
      const int r6 = slot & 63;
      uint2 u;
      u.x = pack2(v.x * rn, v.y * rn);
      u.y = pack2(v.z * rn, v.w * rn);
      // lane owns dims 4*lane..4*lane+3 -> kg = lane>>1, elem base 4*(lane&1)
      *reinterpret_cast<uint2*>(
          apack + (((size_t)t * 32 + (lane >> 1)) * 64 + r6) * 8 + (lane & 1) * 4) = u;
    }
  }
  *reinterpret_cast<float4*>(&wpart[w][lane * 4]) = vs;
  __syncthreads();

  float s = 0.f;
  if (tid < DIM) {
    #pragma unroll
    for (int ww = 0; ww < 8; ++ww) s += wpart[ww][tid];
  }
  float sq = s * s;
  sq += __shfl_xor(sq, 1, 64);
  sq += __shfl_xor(sq, 2, 64);
  sq += __shfl_xor(sq, 4, 64);
  sq += __shfl_xor(sq, 8, 64);
  sq += __shfl_xor(sq, 16, 64);
  sq += __shfl_xor(sq, 32, 64);
  if (tid < DIM && (tid & 63) == 0) wsum[tid >> 6] = sq;
  __syncthreads();
  if (tid == 0) ninv_s = rsqrtf(fmaxf(wsum[0] + wsum[1] + wsum[2] + wsum[3], 1e-30f));
  __syncthreads();
  if (tid < DIM)
    qpack[((tid >> 3) * NCLS + c) * 8 + (tid & 7)] = f2bf(s * ninv_s);
}

// --------- kernel 3 (primary): MFMA GEMM + max-free log-softmax ----------
// 8 waves, each: 64 rows x 64 cols. Target col for whole block = blockIdx>>1.
__global__ __launch_bounds__(512) void k_main(
    const u16* __restrict__ apack, const u16* __restrict__ qpack,
    float* __restrict__ lossp) {
  __shared__ u16   Alds[32 * 64 * 8];   // 32 KB, [kg][row][8]
  __shared__ float psum[8][64];
  __shared__ float simt[64];

  const int tid  = threadIdx.x;
  const int t    = blockIdx.x;
  const int w    = tid >> 6;
  const int lane = tid & 63;

  // stage A tile: 32 KB via global_load_lds, linear, zero VALU
  const u16* gA = apack + (size_t)t * (32 * 64 * 8);
  #pragma unroll
  for (int i = 0; i < 4; ++i) {
    const u16* g = gA + ((w * 4 + i) * 64 + lane) * 8;
    u16* l = &Alds[(w * 4 + i) * 64 * 8];
    __builtin_amdgcn_global_load_lds(
        (const __attribute__((address_space(1))) unsigned*)g,
        (__attribute__((address_space(3))) unsigned*)l, 16, 0, 0);
  }
  __syncthreads();

  const int lg = lane >> 4, l15 = lane & 15;
  f32x4 acc[4][4];
  #pragma unroll
  for (int m = 0; m < 4; ++m)
    #pragma unroll
    for (int n = 0; n < 4; ++n) acc[m][n] = (f32x4)0.f;

  const bf16x8* ap = reinterpret_cast<const bf16x8*>(Alds);
  const bf16x8* bp = reinterpret_cast<const bf16x8*>(qpack);
  const int bbase = w * 64 + l15;       // + n*16

  bf16x8 b0[4], b1[4];
  #pragma unroll
  for (int n = 0; n < 4; ++n) b0[n] = bp[lg * NCLS + bbase + n * 16];

  #pragma unroll 1
  for (int kk = 0; kk < 8; kk += 2) {
    #pragma unroll
    for (int n = 0; n < 4; ++n)
      b1[n] = bp[((kk + 1) * 4 + lg) * NCLS + bbase + n * 16];
    {
      bf16x8 a[4];
      #pragma unroll
      for (int m = 0; m < 4; ++m) a[m] = ap[(kk * 4 + lg) * 64 + m * 16 + l15];
      #pragma unroll
      for (int m = 0; m < 4; ++m)
        #pragma unroll
        for (int n = 0; n < 4; ++n)
          acc[m][n] = __builtin_amdgcn_mfma_f32_16x16x32_bf16(a[m], b0[n], acc[m][n], 0, 0, 0);
    }
    const int k2 = (kk + 2) & 7;
    #pragma unroll
    for (int n = 0; n < 4; ++n)
      b0[n] = bp[(k2 * 4 + lg) * NCLS + bbase + n * 16];
    {
      bf16x8 a[4];
      #pragma unroll
      for (int m = 0; m < 4; ++m) a[m] = ap[((kk + 1) * 4 + lg) * 64 + m * 16 + l15];
      #pragma unroll
      for (int m = 0; m < 4; ++m)
        #pragma unroll
        for (int n = 0; n < 4; ++n)
          acc[m][n] = __builtin_amdgcn_mfma_f32_16x16x32_bf16(a[m], b1[n], acc[m][n], 0, 0, 0);
    }
  }

  // epilogue: sims in [-1,1] -> no max pass needed
  const int cstar = t >> 1;
  const int wstar = cstar >> 6, nstar = (cstar >> 4) & 3, lstar = cstar & 15;
  #pragma unroll
  for (int m = 0; m < 4; ++m) {
    #pragma unroll
    for (int reg = 0; reg < 4; ++reg) {
      float s = __expf(acc[m][0][reg]) + __expf(acc[m][1][reg]) +
                __expf(acc[m][2][reg]) + __expf(acc[m][3][reg]);
      s += __shfl_xor(s, 1, 64);
      s += __shfl_xor(s, 2, 64);
      s += __shfl_xor(s, 4, 64);
      s += __shfl_xor(s, 8, 64);
      const int r = m * 16 + lg * 4 + reg;
      if (l15 == 0) psum[w][r] = s;
      if (w == wstar && l15 == lstar) simt[r] = acc[m][nstar][reg];
    }
  }
  __syncthreads();
  if (tid < 64) {
    const int r = tid;
    float sum = 0.f;
    #pragma unroll
    for (int ww = 0; ww < 8; ++ww) sum += psum[ww][r];
    float lr = __logf(sum) - simt[r];
    lr += __shfl_xor(lr, 1, 64);
    lr += __shfl_xor(lr, 2, 64);
    lr += __shfl_xor(lr, 4, 64);
    lr += __shfl_xor(lr, 8, 64);
    lr += __shfl_xor(lr, 16, 64);
    lr += __shfl_xor(lr, 32, 64);
    if (tid == 0) lossp[t] = lr;
  }
}

// --------- kernel 3 (fallback, round-2 verbatim): reads x directly ----------
__global__ __launch_bounds__(512) void k_main_fb(
    const float* __restrict__ x, const int* __restrict__ tgt,
    const u16* __restrict__ qpack, float* __restrict__ lossp) {
  __shared__ u16   apack[32 * BM * 8];
  __shared__ float pmax[4][BM];
  __shared__ float psum[4][BM];
  __shared__ float simt[BM];
  __shared__ int   ltgt[BM];

  const int tid = threadIdx.x;
  const int i0  = blockIdx.x * BM;
  {
    const int row  = tid >> 3;
    const int part = tid & 7;
    float4 v[8];
    const float4* xr = reinterpret_cast<const float4*>(
        x + (size_t)(i0 + row) * DIM + part * 32);
    #pragma unroll
    for (int j = 0; j < 8; ++j) v[j] = xr[j];
    float ss = 0.f;
    #pragma unroll
    for (int j = 0; j < 8; ++j)
      ss += v[j].x * v[j].x + v[j].y * v[j].y + v[j].z * v[j].z + v[j].w * v[j].w;
    ss += __shfl_xor(ss, 1, 64);
    ss += __shfl_xor(ss, 2, 64);
    ss += __shfl_xor(ss, 4, 64);
    const float rn = rsqrtf(fmaxf(ss, 1e-30f));
    #pragma unroll
    for (int jj = 0; jj < 4; ++jj) {
      uint4 wv;
      wv.x = pack2(v[2*jj].x * rn,   v[2*jj].y * rn);
      wv.y = pack2(v[2*jj].z * rn,   v[2*jj].w * rn);
      wv.z = pack2(v[2*jj+1].x * rn, v[2*jj+1].y * rn);
      wv.w = pack2(v[2*jj+1].z * rn, v[2*jj+1].w * rn);
      const int kg = part * 4 + jj;
      *reinterpret_cast<uint4*>(&apack[(kg * BM + row) * 8]) = wv;
    }
  }
  if (tid < BM) ltgt[tid] = tgt[i0 + tid];
  __syncthreads();

  const int w    = tid >> 6;
  const int lane = tid & 63;
  const int wr = w >> 2, wc = w & 3;
  const int lg = lane >> 4, l15 = lane & 15;

  f32x4 acc[2][8];
  #pragma unroll
  for (int m = 0; m < 2; ++m)
    #pragma unroll
    for (int n = 0; n < 8; ++n) acc[m][n] = (f32x4)0.f;

  const bf16x8* ap = reinterpret_cast<const bf16x8*>(apack);
  const bf16x8* bp = reinterpret_cast<const bf16x8*>(qpack);
  const int bbase = wc * 128 + l15;

  bf16x8 b0[8], b1[8];
  #pragma unroll
  for (int n = 0; n < 8; ++n) b0[n] = bp[lg * NCLS + bbase + n * 16];

  #pragma unroll 1
  for (int kk = 0; kk < 8; kk += 2) {
    #pragma unroll
    for (int n = 0; n < 8; ++n)
      b1[n] = bp[((kk + 1) * 4 + lg) * NCLS + bbase + n * 16];
    {
      const bf16x8 a0 = ap[(kk * 4 + lg) * BM + wr * 32 + l15];
      const bf16x8 a1 = ap[(kk * 4 + lg) * BM + wr * 32 + 16 + l15];
      #pragma unroll
      for (int n = 0; n < 8; ++n) {
        acc[0][n] = __builtin_amdgcn_mfma_f32_16x16x32_bf16(a0, b0[n], acc[0][n], 0, 0, 0);
        acc[1][n] = __builtin_amdgcn_mfma_f32_16x16x32_bf16(a1, b0[n], acc[1][n], 0, 0, 0);
      }
    }
    const int k2 = (kk + 2) & 7;
    #pragma unroll
    for (int n = 0; n < 8; ++n)
      b0[n] = bp[(k2 * 4 + lg) * NCLS + bbase + n * 16];
    {
      const bf16x8 a0 = ap[((kk + 1) * 4 + lg) * BM + wr * 32 + l15];
      const bf16x8 a1 = ap[((kk + 1) * 4 + lg) * BM + wr * 32 + 16 + l15];
      #pragma unroll
      for (int n = 0; n < 8; ++n) {
        acc[0][n] = __builtin_amdgcn_mfma_f32_16x16x32_bf16(a0, b1[n], acc[0][n], 0, 0, 0);
        acc[1][n] = __builtin_amdgcn_mfma_f32_16x16x32_bf16(a1, b1[n], acc[1][n], 0, 0, 0);
      }
    }
  }

  #pragma unroll
  for (int m = 0; m < 2; ++m) {
    #pragma unroll
    for (int reg = 0; reg < 4; ++reg) {
      float mx = acc[m][0][reg];
      #pragma unroll
      for (int n = 1; n < 8; ++n) mx = fmaxf(mx, acc[m][n][reg]);
      mx = fmaxf(mx, __shfl_xor(mx, 1, 64));
      mx = fmaxf(mx, __shfl_xor(mx, 2, 64));
      mx = fmaxf(mx, __shfl_xor(mx, 4, 64));
      mx = fmaxf(mx, __shfl_xor(mx, 8, 64));
      const int r = wr * 32 + m * 16 + lg * 4 + reg;
      if (l15 == 0) pmax[wc][r] = mx;
    }
  }
  __syncthreads();
  #pragma unroll
  for (int m = 0; m < 2; ++m) {
    #pragma unroll
    for (int reg = 0; reg < 4; ++reg) {
      const int r = wr * 32 + m * 16 + lg * 4 + reg;
      const float gm = fmaxf(fmaxf(pmax[0][r], pmax[1][r]),
                             fmaxf(pmax[2][r], pmax[3][r]));
      float s = 0.f;
      #pragma unroll
      for (int n = 0; n < 8; ++n) s += __expf(acc[m][n][reg] - gm);
      s += __shfl_xor(s, 1, 64);
      s += __shfl_xor(s, 2, 64);
      s += __shfl_xor(s, 4, 64);
      s += __shfl_xor(s, 8, 64);
      if (l15 == 0) psum[wc][r] = s;
      const int tg = ltgt[r];
      if ((tg >> 7) == wc && (tg & 15) == l15) {
        const int nt = (tg >> 4) & 7;
        float pv = acc[m][0][reg];
        #pragma unroll
        for (int n = 1; n < 8; ++n) pv = (nt == n) ? acc[m][n][reg] : pv;
        simt[r] = pv;
      }
    }
  }
  __syncthreads();
  if (tid < BM) {
    const int r = tid;
    const float gm = fmaxf(fmaxf(pmax[0][r], pmax[1][r]),
                           fmaxf(pmax[2][r], pmax[3][r]));
    const float sum = psum[0][r] + psum[1][r] + psum[2][r] + psum[3][r];
    float lr = __logf(sum) + gm - simt[r];
    lr += __shfl_xor(lr, 1, 64);
    lr += __shfl_xor(lr, 2, 64);
    lr += __shfl_xor(lr, 4, 64);
    lr += __shfl_xor(lr, 8, 64);
    lr += __shfl_xor(lr, 16, 64);
    lr += __shfl_xor(lr, 32, 64);
    if (tid == 0) lossp[blockIdx.x] = lr;
  }
}

// ---------------------- kernel 4: final mean reduction ----------------------
__global__ __launch_bounds__(256) void k_finalize(
    const float* __restrict__ lossp, float* __restrict__ out) {
  const int tid = threadIdx.x;
  float s = 0.f;
  for (int i = tid; i < NBLK; i += 256) s += lossp[i];
  #pragma unroll
  for (int off = 32; off >= 1; off >>= 1) s += __shfl_xor(s, off, 64);
  __shared__ float ws4[4];
  if ((tid & 63) == 0) ws4[tid >> 6] = s;
  __syncthreads();
  if (tid == 0) out[0] = (ws4[0] + ws4[1] + ws4[2] + ws4[3]) / (float)NROWS;
}

extern "C" void kernel_launch(void* const* d_in, const int* in_sizes, int n_in,
                              void* d_out, int out_size, void* d_ws, size_t ws_size,
                              hipStream_t stream) {
  const float* x   = (const float*)d_in[0];
  const int*   tgt = (const int*)d_in[1];
  float* ws    = (float*)d_ws;
  int*   cnt   = (int*)ws + WS_CNT_I;
  int*   idx   = (int*)ws + WS_IDX_I;
  u16*   qpack = (u16*)(ws + WS_QPACK_F);
  float* lossp = ws + WS_LOSSP_F;
  u16*   apack = (u16*)(ws + WS_APACK_F);

  k_zero<<<1, 512, 0, stream>>>(cnt);
  k_scatter<<<NROWS / 256, 256, 0, stream>>>(tgt, cnt, idx);
  if (ws_size >= WS_NEEDED) {
    k_csum<true><<<NCLS, 512, 0, stream>>>(x, idx, qpack, apack);
    k_main<<<NBLK, 512, 0, stream>>>(apack, qpack, lossp);
  } else {
    k_csum<false><<<NCLS, 512, 0, stream>>>(x, idx, qpack, apack);
    k_main_fb<<<NBLK, 512, 0, stream>>>(x, tgt, qpack, lossp);
  }
  k_finalize<<<1, 256, 0, stream>>>(lossp, (float*)d_out);
}